// Round 16
// baseline (764.967 us; speedup 1.0000x reference)
//
#include <hip/hip_runtime.h>
#include <hip/hip_fp16.h>

#define NN 10000
#define TT 64
#define PP 64
#define HH 128
#define EE 320000

typedef _Float16 half8 __attribute__((ext_vector_type(8)));
typedef float f32x4 __attribute__((ext_vector_type(4)));

// gates: hardware exp + v_rcp_f32 divide (R15-proven: absmax 0.031 < 0.105)
__device__ __forceinline__ float sigm(float x) {
    return __builtin_amdgcn_rcpf(1.0f + __expf(-x));
}
__device__ __forceinline__ float tanh_(float x) {
    return 1.0f - 2.0f * __builtin_amdgcn_rcpf(__expf(2.0f * x) + 1.0f);
}
// swizzled byte offset into a [rows][128] fp16 LDS tile (row stride 256B).
__device__ __forceinline__ int hswz(int row, int colbyte) {
    return row * 256 + (colbyte ^ ((row & 7) << 4));
}

// ---------------- weight pack: [Wih | Whh] row-major -> fp16 ----------------
__global__ void pack_w_kernel(const float* __restrict__ Wa, int Ka,
                              const float* __restrict__ Wb,
                              _Float16* __restrict__ out, int total) {
    int idx = blockIdx.x * 256 + threadIdx.x;
    if (idx >= total) return;
    int K = Ka + HH;
    int r = idx / K, k = idx - r * K;
    float v = (k < Ka) ? Wa[r * Ka + k] : Wb[r * HH + (k - Ka)];
    out[idx] = (_Float16)v;
}

// -- fused 2-layer GRU: 48 rows/block, 1 dispatch round, resident weights --
// R15 analysis: T = rounds x 65 phases x (fixed ~2440cy + work). 625 blocks =
// 3 rounds. Here: 48 rows (3 mfrags) per block -> grid 209 <= 256 CUs -> ONE
// round; per-phase work triples but fixed stall is amortized. Register scheme
// = R15-proven: resident 36 frags (L0h 12 + L1 24) = 144 "+a"; L0 x-part in
// LDS; per-mf state transient; hold re-read from LDS (no carried hp).
// LDS 96KB dynamic: [0,24K) H0 ping/pong | [24K,48K) H1 | [48K,96K) W0x.
__global__ __launch_bounds__(512, 1) void gru2_t8_kernel(
    const float* __restrict__ x, int T, int xstride,
    const _Float16* __restrict__ W0,  // [384][192]  (64 x | 128 h)
    const float* __restrict__ bih0, const float* __restrict__ bhh0,
    const _Float16* __restrict__ W1,  // [384][256]  (128 y0 | 128 h)
    const float* __restrict__ bih1, const float* __restrict__ bhh1,
    float* __restrict__ hout)         // [NN][128] f32
{
    extern __shared__ __align__(16) char lds[];
    char* const H0B = lds;                 // 2 x 12K ping/pong
    char* const H1B = lds + 24576;
    char* const WX  = lds + 49152;         // 48KB staged L0 x-part weights
    const int tid = threadIdx.x;
    const int wv = tid >> 6;          // 0..7 = gate-col triple
    const int lane = tid & 63;
    const int l15 = lane & 15, lg = lane >> 4;
    const int rowbase = blockIdx.x * 48;
    const int col = wv * 16 + l15;

    for (int i = tid; i < 12288; i += 512) ((int*)lds)[i] = 0;

    // ---- stage L0 x-part weights (6 frags/wave) into LDS ----
    #pragma unroll
    for (int g = 0; g < 3; ++g) {
        const _Float16* r0 = W0 + ((size_t)((g * 8 + wv) * 16 + l15)) * 192;
        #pragma unroll
        for (int kt = 0; kt < 2; ++kt)
            *(half8*)(WX + wv * 6144 + (g * 2 + kt) * 1024 + lane * 16) =
                *(const half8*)(r0 + kt * 32 + lg * 8);
    }

    // ---- resident weights: L0 h-part (12) + L1 (24), pinned "+a" (144 regs) ----
    half8 w0h[3][4], w1[3][8];
    #pragma unroll
    for (int g = 0; g < 3; ++g) {
        const _Float16* r0 = W0 + ((size_t)((g * 8 + wv) * 16 + l15)) * 192;
        #pragma unroll
        for (int kt = 0; kt < 4; ++kt) w0h[g][kt] = *(const half8*)(r0 + 64 + kt * 32 + lg * 8);
        const _Float16* r1 = W1 + ((size_t)((g * 8 + wv) * 16 + l15)) * 256;
        #pragma unroll
        for (int kt = 0; kt < 8; ++kt) w1[g][kt] = *(const half8*)(r1 + kt * 32 + lg * 8);
    }
    #pragma unroll
    for (int g = 0; g < 3; ++g) {
        #pragma unroll
        for (int kt = 0; kt < 4; ++kt) asm volatile("" : "+a"(w0h[g][kt]));
        #pragma unroll
        for (int kt = 0; kt < 8; ++kt) asm volatile("" : "+a"(w1[g][kt]));
    }

    // ---- biases folded into accumulator init (n split: n = tanh(i_n + r*h_n)) ----
    const float br0  = bih0[col] + bhh0[col];
    const float bz0  = bih0[128 + col] + bhh0[128 + col];
    const float bni0 = bih0[256 + col];
    const float bnh0 = bhh0[256 + col];
    const float br1  = bih1[col] + bhh1[col];
    const float bz1  = bih1[128 + col] + bhh1[128 + col];
    const float bni1 = bih1[256 + col];
    const float bnh1 = bhh1[256 + col];

    // per-mf x row pointers, clamped (last block covers rows to 10032 > NN)
    const float* xr[3];
    #pragma unroll
    for (int mf = 0; mf < 3; ++mf) {
        int rr = rowbase + mf * 16 + l15;
        if (rr > NN - 1) rr = NN - 1;
        xr[mf] = x + (size_t)rr * xstride;
    }

    __syncthreads();

    for (int it = 0; it <= T; ++it) {
        const int off = (it & 1) * 12288;
        char* const H0r = H0B + off;                 // h0(it-1) == y0(it-1)
        char* const H0w = H0B + (12288 - off);       // h0(it)
        char* const H1r = H1B + off;                 // h1(it-2)
        char* const H1w = H1B + (12288 - off);       // h1(it-1)

        #pragma unroll
        for (int mf = 0; mf < 3; ++mf) {
            const int arow = mf * 16 + l15;

            // issue x(it) loads for this mf (latency hides under L1 below)
            float4 xu0, xv0, xu1, xv1;
            if (it < T) {
                const float* p = xr[mf] + it * PP;
                xu0 = *(const float4*)(p + lg * 8);
                xv0 = *(const float4*)(p + lg * 8 + 4);
                xu1 = *(const float4*)(p + 32 + lg * 8);
                xv1 = *(const float4*)(p + 32 + lg * 8 + 4);
            }

            // ===== layer 1: h1(it-1) = f(y0(it-1), h1(it-2)) — no x dep =====
            if (it >= 1) {
                f32x4 ar  = {br1, br1, br1, br1};
                f32x4 az  = {bz1, bz1, bz1, bz1};
                f32x4 ani = {bni1, bni1, bni1, bni1};
                f32x4 anh = {bnh1, bnh1, bnh1, bnh1};
                #pragma unroll
                for (int kt = 0; kt < 4; ++kt) {
                    const int boff = (kt * 32 + lg * 8) * 2;
                    half8 ay  = *(const half8*)(H0r + hswz(arow, boff));
                    half8 ah1 = *(const half8*)(H1r + hswz(arow, boff));
                    ar  = __builtin_amdgcn_mfma_f32_16x16x32_f16(ay,  w1[0][kt],   ar, 0,0,0);
                    ar  = __builtin_amdgcn_mfma_f32_16x16x32_f16(ah1, w1[0][4+kt], ar, 0,0,0);
                    az  = __builtin_amdgcn_mfma_f32_16x16x32_f16(ay,  w1[1][kt],   az, 0,0,0);
                    az  = __builtin_amdgcn_mfma_f32_16x16x32_f16(ah1, w1[1][4+kt], az, 0,0,0);
                    ani = __builtin_amdgcn_mfma_f32_16x16x32_f16(ay,  w1[2][kt],   ani, 0,0,0);
                    anh = __builtin_amdgcn_mfma_f32_16x16x32_f16(ah1, w1[2][4+kt], anh, 0,0,0);
                }
                #pragma unroll
                for (int r = 0; r < 4; ++r) {
                    const int drow = mf * 16 + lg * 4 + r;
                    float hold = (float)(*(const _Float16*)(H1r + hswz(drow, col * 2)));
                    float rg = sigm(ar[r]);
                    float zg = sigm(az[r]);
                    float ng = tanh_(ani[r] + rg * anh[r]);
                    float hv = ng + zg * (hold - ng);
                    *(_Float16*)(H1w + hswz(drow, col * 2)) = (_Float16)hv;
                    if (it == T) {
                        const int grow = rowbase + drow;
                        if (grow < NN) hout[(size_t)grow * HH + col] = hv;
                    }
                }
            }

            // ===== layer 0: h0(it) = f(x(it), h0(it-1)) =====
            if (it < T) {
                half8 ax0, ax1;
                ax0[0]=(_Float16)xu0.x; ax0[1]=(_Float16)xu0.y; ax0[2]=(_Float16)xu0.z; ax0[3]=(_Float16)xu0.w;
                ax0[4]=(_Float16)xv0.x; ax0[5]=(_Float16)xv0.y; ax0[6]=(_Float16)xv0.z; ax0[7]=(_Float16)xv0.w;
                ax1[0]=(_Float16)xu1.x; ax1[1]=(_Float16)xu1.y; ax1[2]=(_Float16)xu1.z; ax1[3]=(_Float16)xu1.w;
                ax1[4]=(_Float16)xv1.x; ax1[5]=(_Float16)xv1.y; ax1[6]=(_Float16)xv1.z; ax1[7]=(_Float16)xv1.w;
                f32x4 ar  = {br0, br0, br0, br0};
                f32x4 az  = {bz0, bz0, bz0, bz0};
                f32x4 ani = {bni0, bni0, bni0, bni0};
                f32x4 anh = {bnh0, bnh0, bnh0, bnh0};
                // x-part: B-frags from LDS (staged once)
                #pragma unroll
                for (int kt = 0; kt < 2; ++kt) {
                    const char* wb = WX + wv * 6144 + kt * 1024 + lane * 16;
                    half8 wxr = *(const half8*)(wb);
                    half8 wxz = *(const half8*)(wb + 2048);
                    half8 wxn = *(const half8*)(wb + 4096);
                    half8 ax = (kt == 0) ? ax0 : ax1;
                    ar  = __builtin_amdgcn_mfma_f32_16x16x32_f16(ax, wxr, ar, 0,0,0);
                    az  = __builtin_amdgcn_mfma_f32_16x16x32_f16(ax, wxz, az, 0,0,0);
                    ani = __builtin_amdgcn_mfma_f32_16x16x32_f16(ax, wxn, ani, 0,0,0);
                }
                // h-part: resident B-frags
                #pragma unroll
                for (int kt = 0; kt < 4; ++kt) {
                    half8 ah = *(const half8*)(H0r + hswz(arow, (kt * 32 + lg * 8) * 2));
                    ar  = __builtin_amdgcn_mfma_f32_16x16x32_f16(ah, w0h[0][kt], ar, 0,0,0);
                    az  = __builtin_amdgcn_mfma_f32_16x16x32_f16(ah, w0h[1][kt], az, 0,0,0);
                    anh = __builtin_amdgcn_mfma_f32_16x16x32_f16(ah, w0h[2][kt], anh, 0,0,0);
                }
                #pragma unroll
                for (int r = 0; r < 4; ++r) {
                    const int drow = mf * 16 + lg * 4 + r;
                    float hold = (float)(*(const _Float16*)(H0r + hswz(drow, col * 2)));
                    float rg = sigm(ar[r]);
                    float zg = sigm(az[r]);
                    float ng = tanh_(ani[r] + rg * anh[r]);
                    float hv = ng + zg * (hold - ng);
                    *(_Float16*)(H0w + hswz(drow, col * 2)) = (_Float16)hv;
                }
            }
        }
        __syncthreads();
    }
}

// ---------------- GAT: per-node h, attention logits, zero accumulators ----------------
__global__ void gat_node_kernel(const float* __restrict__ Xseq, const float* __restrict__ W,
                                const float* __restrict__ att_s, const float* __restrict__ att_d,
                                float* __restrict__ h, float* __restrict__ a_s, float* __restrict__ a_d,
                                float* __restrict__ denom, float* __restrict__ accum) {
    __shared__ float sW[64][33];
    __shared__ float sas[32], sad[32];
    int tid = threadIdx.x;
    for (int i = tid; i < 64 * 32; i += 256) sW[i >> 5][i & 31] = W[i];
    if (tid < 32) { sas[tid] = att_s[tid]; sad[tid] = att_d[tid]; }
    __syncthreads();
    int c = tid & 31;
    int n = blockIdx.x * 8 + (tid >> 5);
    const float* xr = Xseq + (size_t)n * (TT * PP) + 63 * PP;
    float acc = 0.f;
    #pragma unroll
    for (int k = 0; k < 64; ++k) acc += xr[k] * sW[k][c];
    h[n * 32 + c] = acc;
    accum[n * 32 + c] = 0.f;
    float ps = acc * sas[c];
    float pd = acc * sad[c];
    #pragma unroll
    for (int m = 16; m > 0; m >>= 1) { ps += __shfl_xor(ps, m, 32); pd += __shfl_xor(pd, m, 32); }
    if (c == 0) { a_s[n] = ps; a_d[n] = pd; denom[n] = 0.f; }
}

// ---------------- GAT: fused edge pass (denom + weighted accum; div postponed) ----------------
__global__ void gat_edge_kernel(const int* __restrict__ ei,
                                const float* __restrict__ a_s, const float* __restrict__ a_d,
                                const float* __restrict__ h,
                                float* __restrict__ denom, float* __restrict__ accum) {
    int gid = blockIdx.x * 256 + threadIdx.x;
    int e = gid >> 5, c = gid & 31;
    if (e >= EE + NN) return;
    int src, dst;
    if (e < EE) { src = ei[e]; dst = ei[EE + e]; }
    else        { src = e - EE; dst = src; }          // self-loops
    float s = a_s[src] + a_d[dst];
    float le = (s > 0.f) ? s : 0.2f * s;              // leaky_relu 0.2
    float ex = __expf(le);                             // softmax shift cancels exactly
    unsafeAtomicAdd(&accum[dst * 32 + c], ex * h[src * 32 + c]);
    if (c == 0) unsafeAtomicAdd(&denom[dst], ex);
}

// ---------------- residual = X_t - concat([gat_out, 0]) ----------------
__global__ void residual_kernel(const float* __restrict__ Xseq, const float* __restrict__ accum,
                                const float* __restrict__ denom, const float* __restrict__ bias,
                                float* __restrict__ res) {
    int idx = blockIdx.x * 256 + threadIdx.x;
    if (idx >= NN * 64) return;
    int n = idx >> 6, k = idx & 63;
    float xv = Xseq[(size_t)n * (TT * PP) + 63 * PP + k];
    float g = 0.f;
    if (k < 32) g = accum[n * 32 + k] / denom[n] + bias[k];
    res[idx] = xv - g;
}

// ---------------- projections -> raw features in d_out ----------------
__global__ void proj_kernel(const float* __restrict__ ht, const float* __restrict__ hcs,
                            const float* __restrict__ Wt, const float* __restrict__ bt,
                            const float* __restrict__ Wc, const float* __restrict__ bc,
                            float* __restrict__ out) {
    __shared__ float sW[32][129];
    __shared__ float sb[32];
    int tid = threadIdx.x;
    for (int i = tid; i < 16 * 128; i += 256) {
        sW[i >> 7][i & 127] = Wt[i];
        sW[16 + (i >> 7)][i & 127] = Wc[i];
    }
    if (tid < 16) { sb[tid] = bt[tid]; sb[16 + tid] = bc[tid]; }
    __syncthreads();
    int idx = blockIdx.x * 256 + tid;
    int n = idx >> 5, c = idx & 31;
    const float* hrow = ((c < 16) ? ht : hcs) + (size_t)n * HH;
    const float* wrow = sW[c];
    float acc = sb[c];
    #pragma unroll 8
    for (int k = 0; k < 128; ++k) acc += hrow[k] * wrow[k];
    out[idx] = acc;
}

// ---------------- batchnorm stats (one block per column, no atomics) ----------------
__global__ void bn_stats_kernel(const float* __restrict__ raw,
                                const float* __restrict__ g1, const float* __restrict__ b1,
                                const float* __restrict__ g2, const float* __restrict__ b2,
                                float* __restrict__ ss) {
    int c = blockIdx.x;
    int tid = threadIdx.x;
    float s = 0.f, q = 0.f;
    for (int n = tid; n < NN; n += 256) {
        float v = raw[n * 32 + c];
        s += v; q += v * v;
    }
    __shared__ float ls[256], lq[256];
    ls[tid] = s; lq[tid] = q;
    __syncthreads();
    for (int st = 128; st > 0; st >>= 1) {
        if (tid < st) { ls[tid] += ls[tid + st]; lq[tid] += lq[tid + st]; }
        __syncthreads();
    }
    if (tid == 0) {
        float m = ls[0] / (float)NN;
        float var = lq[0] / (float)NN - m * m;      // biased var, matches jnp.var
        float istd = rsqrtf(var + 1e-5f);
        float gg = (c < 16) ? g1[c] : g2[c - 16];
        float bb = (c < 16) ? b1[c] : b2[c - 16];
        float sc = istd * gg;
        ss[c] = sc;
        ss[32 + c] = bb - m * sc;
    }
}

__global__ void bn_apply_kernel(float* __restrict__ out, const float* __restrict__ ss) {
    int idx = blockIdx.x * 256 + threadIdx.x;
    if (idx >= NN * 32) return;
    int c = idx & 31;
    out[idx] = out[idx] * ss[c] + ss[32 + c];
}

extern "C" void kernel_launch(void* const* d_in, const int* in_sizes, int n_in,
                              void* d_out, int out_size, void* d_ws, size_t ws_size,
                              hipStream_t stream) {
    const float* Xseq  = (const float*)d_in[0];
    const int*   ei    = (const int*)d_in[1];
    const float* tWih0 = (const float*)d_in[2];
    const float* tWhh0 = (const float*)d_in[3];
    const float* tbih0 = (const float*)d_in[4];
    const float* tbhh0 = (const float*)d_in[5];
    const float* tWih1 = (const float*)d_in[6];
    const float* tWhh1 = (const float*)d_in[7];
    const float* tbih1 = (const float*)d_in[8];
    const float* tbhh1 = (const float*)d_in[9];
    const float* cWih0 = (const float*)d_in[10];
    const float* cWhh0 = (const float*)d_in[11];
    const float* cbih0 = (const float*)d_in[12];
    const float* cbhh0 = (const float*)d_in[13];
    const float* cWih1 = (const float*)d_in[14];
    const float* cWhh1 = (const float*)d_in[15];
    const float* cbih1 = (const float*)d_in[16];
    const float* cbhh1 = (const float*)d_in[17];
    const float* gatW  = (const float*)d_in[18];
    const float* atts  = (const float*)d_in[19];
    const float* attd  = (const float*)d_in[20];
    const float* gatb  = (const float*)d_in[21];
    const float* ptW   = (const float*)d_in[22];
    const float* ptb   = (const float*)d_in[23];
    const float* pcW   = (const float*)d_in[24];
    const float* pcb   = (const float*)d_in[25];
    const float* bn1g  = (const float*)d_in[26];
    const float* bn1b  = (const float*)d_in[27];
    const float* bn2g  = (const float*)d_in[28];
    const float* bn2b  = (const float*)d_in[29];

    char* ws = (char*)d_ws;                       // total use ~16.2 MB
    _Float16* Wt0 = (_Float16*)(ws);              // 384*192*2 = 147456
    _Float16* Wt1 = (_Float16*)(ws + 147456);     // 384*256*2 = 196608
    _Float16* Wc0 = (_Float16*)(ws + 344064);
    _Float16* Wc1 = (_Float16*)(ws + 491520);
    float* h_t   = (float*)(ws + 688128);         // 10000*128*4
    float* h_cs  = (float*)(ws + 5808128);
    float* gath  = (float*)(ws + 10928128);       // 10000*32*4
    float* a_s   = (float*)(ws + 12208128);
    float* a_d   = (float*)(ws + 12248128);
    float* denom = (float*)(ws + 12288128);
    float* accum = (float*)(ws + 12328128);       // 10000*32*4
    float* resid = (float*)(ws + 13608128);       // 10000*64*4
    float* ss    = (float*)(ws + 16168128);       // 64 floats

    // allow 96 KB dynamic LDS (gfx950 has 160 KB/CU); host-side, idempotent
    (void)hipFuncSetAttribute((const void*)gru2_t8_kernel,
                              hipFuncAttributeMaxDynamicSharedMemorySize, 98304);

    pack_w_kernel<<<288, 256, 0, stream>>>(tWih0, 64,  tWhh0, Wt0, 384 * 192);
    pack_w_kernel<<<384, 256, 0, stream>>>(tWih1, 128, tWhh1, Wt1, 384 * 256);
    pack_w_kernel<<<288, 256, 0, stream>>>(cWih0, 64,  cWhh0, Wc0, 384 * 192);
    pack_w_kernel<<<384, 256, 0, stream>>>(cWih1, 128, cWhh1, Wc1, 384 * 256);

    gru2_t8_kernel<<<209, 512, 98304, stream>>>(Xseq, TT, TT * PP, Wt0, tbih0, tbhh0,
                                                Wt1, tbih1, tbhh1, h_t);

    gat_node_kernel<<<1250, 256, 0, stream>>>(Xseq, gatW, atts, attd, gath, a_s, a_d, denom, accum);
    gat_edge_kernel<<<41250, 256, 0, stream>>>(ei, a_s, a_d, gath, denom, accum);
    residual_kernel<<<2500, 256, 0, stream>>>(Xseq, accum, denom, gatb, resid);

    gru2_t8_kernel<<<209, 512, 98304, stream>>>(resid, 1, PP, Wc0, cbih0, cbhh0,
                                                Wc1, cbih1, cbhh1, h_cs);

    proj_kernel<<<1250, 256, 0, stream>>>(h_t, h_cs, ptW, ptb, pcW, pcb, (float*)d_out);
    bn_stats_kernel<<<32, 256, 0, stream>>>((const float*)d_out, bn1g, bn1b, bn2g, bn2b, ss);
    bn_apply_kernel<<<1250, 256, 0, stream>>>((float*)d_out, ss);
}

// Round 17
// 591.300 us; speedup vs baseline: 1.2937x; 1.2937x over previous
//
#include <hip/hip_runtime.h>
#include <hip/hip_fp16.h>

#define NN 10000
#define TT 64
#define PP 64
#define HH 128
#define EE 320000

typedef _Float16 half8 __attribute__((ext_vector_type(8)));
typedef float f32x4 __attribute__((ext_vector_type(4)));

// gates: hardware exp + v_rcp_f32 divide (R15-proven: absmax 0.031 < 0.105)
__device__ __forceinline__ float sigm(float x) {
    return __builtin_amdgcn_rcpf(1.0f + __expf(-x));
}
__device__ __forceinline__ float tanh_(float x) {
    return 1.0f - 2.0f * __builtin_amdgcn_rcpf(__expf(2.0f * x) + 1.0f);
}
// swizzled byte offset into a [rows][128] fp16 LDS tile (row stride 256B).
__device__ __forceinline__ int hswz(int row, int colbyte) {
    return row * 256 + (colbyte ^ ((row & 7) << 4));
}

// ---------------- weight pack: [Wih | Whh] row-major -> fp16 ----------------
__global__ void pack_w_kernel(const float* __restrict__ Wa, int Ka,
                              const float* __restrict__ Wb,
                              _Float16* __restrict__ out, int total) {
    int idx = blockIdx.x * 256 + threadIdx.x;
    if (idx >= total) return;
    int K = Ka + HH;
    int r = idx / K, k = idx - r * K;
    float v = (k < Ka) ? Wa[r * Ka + k] : Wb[r * HH + (k - Ka)];
    out[idx] = (_Float16)v;
}

// -- fused 2-layer GRU: 8 waves x 1 triple, 2 waves/SIMD, resident weights --
// R15 structure (best: 472us) + pressure-neutral micro-opts:
//  (1) H0r fragment reads SHARED between L1(y0-input) and L0(h-input) — they
//      are the same addresses; R15 read them twice (-4 ds_read_b128/phase).
//  (2) both h-fragment read sets hoisted to phase top — LDS latency overlaps
//      L1's MFMA cluster instead of stalling L0.
//  (3) s_setprio(1) around MFMA clusters (waves are role-split; T5).
// Resident: 36 frags (L0h 12 + L1 24) = 144 regs "+a"; L0 x-part in LDS;
// carried hp (R16 regression proved dropping it costs); rcp gates.
__global__ __launch_bounds__(512, 2) void gru2_t8_kernel(
    const float* __restrict__ x, int T, int xstride,
    const _Float16* __restrict__ W0,  // [384][192]  (64 x | 128 h)
    const float* __restrict__ bih0, const float* __restrict__ bhh0,
    const _Float16* __restrict__ W1,  // [384][256]  (128 y0 | 128 h)
    const float* __restrict__ bih1, const float* __restrict__ bhh1,
    float* __restrict__ hout)         // [NN][128] f32
{
    __shared__ __align__(16) char lds[65536];  // [0,16K) h ping-pong | [16K,64K) W0x
    char* const WX = lds + 16384;
    const int tid = threadIdx.x;
    const int wv = tid >> 6;          // 0..7 = gate-col triple
    const int lane = tid & 63;
    const int l15 = lane & 15, lg = lane >> 4;
    const int rowbase = blockIdx.x * 16;
    const int col = wv * 16 + l15;

    for (int i = tid; i < 4096; i += 512) ((int*)lds)[i] = 0;

    // ---- stage L0 x-part weights (6 frags/wave) into LDS ----
    #pragma unroll
    for (int g = 0; g < 3; ++g) {
        const _Float16* r0 = W0 + ((size_t)((g * 8 + wv) * 16 + l15)) * 192;
        #pragma unroll
        for (int kt = 0; kt < 2; ++kt)
            *(half8*)(WX + wv * 6144 + (g * 2 + kt) * 1024 + lane * 16) =
                *(const half8*)(r0 + kt * 32 + lg * 8);
    }

    // ---- resident weights: L0 h-part (12) + L1 (24), pinned "+a" (144 regs) ----
    half8 w0h[3][4], w1[3][8];
    #pragma unroll
    for (int g = 0; g < 3; ++g) {
        const _Float16* r0 = W0 + ((size_t)((g * 8 + wv) * 16 + l15)) * 192;
        #pragma unroll
        for (int kt = 0; kt < 4; ++kt) w0h[g][kt] = *(const half8*)(r0 + 64 + kt * 32 + lg * 8);
        const _Float16* r1 = W1 + ((size_t)((g * 8 + wv) * 16 + l15)) * 256;
        #pragma unroll
        for (int kt = 0; kt < 8; ++kt) w1[g][kt] = *(const half8*)(r1 + kt * 32 + lg * 8);
    }
    #pragma unroll
    for (int g = 0; g < 3; ++g) {
        #pragma unroll
        for (int kt = 0; kt < 4; ++kt) asm volatile("" : "+a"(w0h[g][kt]));
        #pragma unroll
        for (int kt = 0; kt < 8; ++kt) asm volatile("" : "+a"(w1[g][kt]));
    }

    // ---- biases folded into accumulator init (n split: n = tanh(i_n + r*h_n)) ----
    const float br0  = bih0[col] + bhh0[col];
    const float bz0  = bih0[128 + col] + bhh0[128 + col];
    const float bni0 = bih0[256 + col];
    const float bnh0 = bhh0[256 + col];
    const float br1  = bih1[col] + bhh1[col];
    const float bz1  = bih1[128 + col] + bhh1[128 + col];
    const float bni1 = bih1[256 + col];
    const float bnh1 = bhh1[256 + col];

    const float* xr = x + (size_t)(rowbase + l15) * xstride;

    float hp0[4] = {0.f, 0.f, 0.f, 0.f};
    float hp1[4] = {0.f, 0.f, 0.f, 0.f};

    __syncthreads();

    for (int it = 0; it <= T; ++it) {
        const int off = (it & 1) * 4096;
        char* const H0r = lds + off;                 // h0(it-1) == y0(it-1)
        char* const H0w = lds + (4096 - off);        // h0(it)
        char* const H1r = lds + 8192 + off;          // h1(it-2)
        char* const H1w = lds + 8192 + (4096 - off); // h1(it-1)

        // issue x(it) loads early; consumed after L1 (latency cover)
        float4 xu0, xv0, xu1, xv1;
        if (it < T) {
            const float* p = xr + it * PP;
            xu0 = *(const float4*)(p + lg * 8);
            xv0 = *(const float4*)(p + lg * 8 + 4);
            xu1 = *(const float4*)(p + 32 + lg * 8);
            xv1 = *(const float4*)(p + 32 + lg * 8 + 4);
        }

        // hoisted shared LDS reads: hy = h0(it-1) fragments (L1's y0-input AND
        // L0's h-input — same addresses); hh1 = h1(it-2) fragments.
        half8 hy[4], hh1[4];
        #pragma unroll
        for (int kt = 0; kt < 4; ++kt) {
            const int boff = (kt * 32 + lg * 8) * 2;
            hy[kt]  = *(const half8*)(H0r + hswz(l15, boff));
            hh1[kt] = *(const half8*)(H1r + hswz(l15, boff));
        }

        // ============ layer 1: h1(it-1) = f(y0(it-1), h1(it-2)) ============
        if (it >= 1) {
            f32x4 ar  = {br1, br1, br1, br1};
            f32x4 az  = {bz1, bz1, bz1, bz1};
            f32x4 ani = {bni1, bni1, bni1, bni1};
            f32x4 anh = {bnh1, bnh1, bnh1, bnh1};
            __builtin_amdgcn_s_setprio(1);
            #pragma unroll
            for (int kt = 0; kt < 4; ++kt) {
                ar  = __builtin_amdgcn_mfma_f32_16x16x32_f16(hy[kt],  w1[0][kt],   ar, 0,0,0);
                ar  = __builtin_amdgcn_mfma_f32_16x16x32_f16(hh1[kt], w1[0][4+kt], ar, 0,0,0);
                az  = __builtin_amdgcn_mfma_f32_16x16x32_f16(hy[kt],  w1[1][kt],   az, 0,0,0);
                az  = __builtin_amdgcn_mfma_f32_16x16x32_f16(hh1[kt], w1[1][4+kt], az, 0,0,0);
                ani = __builtin_amdgcn_mfma_f32_16x16x32_f16(hy[kt],  w1[2][kt],   ani, 0,0,0);
                anh = __builtin_amdgcn_mfma_f32_16x16x32_f16(hh1[kt], w1[2][4+kt], anh, 0,0,0);
            }
            __builtin_amdgcn_s_setprio(0);
            #pragma unroll
            for (int r = 0; r < 4; ++r) {
                float rg = sigm(ar[r]);
                float zg = sigm(az[r]);
                float ng = tanh_(ani[r] + rg * anh[r]);
                float hv = ng + zg * (hp1[r] - ng);
                hp1[r] = hv;
                *(_Float16*)(H1w + hswz(lg * 4 + r, col * 2)) = (_Float16)hv;
            }
        }

        // ============ layer 0: h0(it) = f(x(it), h0(it-1)) ============
        if (it < T) {
            half8 ax0, ax1;
            ax0[0]=(_Float16)xu0.x; ax0[1]=(_Float16)xu0.y; ax0[2]=(_Float16)xu0.z; ax0[3]=(_Float16)xu0.w;
            ax0[4]=(_Float16)xv0.x; ax0[5]=(_Float16)xv0.y; ax0[6]=(_Float16)xv0.z; ax0[7]=(_Float16)xv0.w;
            ax1[0]=(_Float16)xu1.x; ax1[1]=(_Float16)xu1.y; ax1[2]=(_Float16)xu1.z; ax1[3]=(_Float16)xu1.w;
            ax1[4]=(_Float16)xv1.x; ax1[5]=(_Float16)xv1.y; ax1[6]=(_Float16)xv1.z; ax1[7]=(_Float16)xv1.w;
            f32x4 ar  = {br0, br0, br0, br0};
            f32x4 az  = {bz0, bz0, bz0, bz0};
            f32x4 ani = {bni0, bni0, bni0, bni0};
            f32x4 anh = {bnh0, bnh0, bnh0, bnh0};
            __builtin_amdgcn_s_setprio(1);
            // x-part: B-frags from LDS (staged once)
            #pragma unroll
            for (int kt = 0; kt < 2; ++kt) {
                const char* wb = WX + wv * 6144 + kt * 1024 + lane * 16;
                half8 wxr = *(const half8*)(wb);
                half8 wxz = *(const half8*)(wb + 2048);
                half8 wxn = *(const half8*)(wb + 4096);
                half8 ax = (kt == 0) ? ax0 : ax1;
                ar  = __builtin_amdgcn_mfma_f32_16x16x32_f16(ax, wxr, ar, 0,0,0);
                az  = __builtin_amdgcn_mfma_f32_16x16x32_f16(ax, wxz, az, 0,0,0);
                ani = __builtin_amdgcn_mfma_f32_16x16x32_f16(ax, wxn, ani, 0,0,0);
            }
            // h-part: resident B-frags, shared hy A-frags
            #pragma unroll
            for (int kt = 0; kt < 4; ++kt) {
                ar  = __builtin_amdgcn_mfma_f32_16x16x32_f16(hy[kt], w0h[0][kt], ar, 0,0,0);
                az  = __builtin_amdgcn_mfma_f32_16x16x32_f16(hy[kt], w0h[1][kt], az, 0,0,0);
                anh = __builtin_amdgcn_mfma_f32_16x16x32_f16(hy[kt], w0h[2][kt], anh, 0,0,0);
            }
            __builtin_amdgcn_s_setprio(0);
            #pragma unroll
            for (int r = 0; r < 4; ++r) {
                float rg = sigm(ar[r]);
                float zg = sigm(az[r]);
                float ng = tanh_(ani[r] + rg * anh[r]);
                float hv = ng + zg * (hp0[r] - ng);
                hp0[r] = hv;
                *(_Float16*)(H0w + hswz(lg * 4 + r, col * 2)) = (_Float16)hv;
            }
        }
        __syncthreads();
    }

    // final h1 from carried registers
    #pragma unroll
    for (int r = 0; r < 4; ++r)
        hout[(size_t)(rowbase + lg * 4 + r) * HH + col] = hp1[r];
}

// ---------------- GAT: per-node h, attention logits, zero accumulators ----------------
__global__ void gat_node_kernel(const float* __restrict__ Xseq, const float* __restrict__ W,
                                const float* __restrict__ att_s, const float* __restrict__ att_d,
                                float* __restrict__ h, float* __restrict__ a_s, float* __restrict__ a_d,
                                float* __restrict__ denom, float* __restrict__ accum) {
    __shared__ float sW[64][33];
    __shared__ float sas[32], sad[32];
    int tid = threadIdx.x;
    for (int i = tid; i < 64 * 32; i += 256) sW[i >> 5][i & 31] = W[i];
    if (tid < 32) { sas[tid] = att_s[tid]; sad[tid] = att_d[tid]; }
    __syncthreads();
    int c = tid & 31;
    int n = blockIdx.x * 8 + (tid >> 5);
    const float* xr = Xseq + (size_t)n * (TT * PP) + 63 * PP;
    float acc = 0.f;
    #pragma unroll
    for (int k = 0; k < 64; ++k) acc += xr[k] * sW[k][c];
    h[n * 32 + c] = acc;
    accum[n * 32 + c] = 0.f;
    float ps = acc * sas[c];
    float pd = acc * sad[c];
    #pragma unroll
    for (int m = 16; m > 0; m >>= 1) { ps += __shfl_xor(ps, m, 32); pd += __shfl_xor(pd, m, 32); }
    if (c == 0) { a_s[n] = ps; a_d[n] = pd; denom[n] = 0.f; }
}

// ---------------- GAT: fused edge pass (denom + weighted accum; div postponed) ----------------
__global__ void gat_edge_kernel(const int* __restrict__ ei,
                                const float* __restrict__ a_s, const float* __restrict__ a_d,
                                const float* __restrict__ h,
                                float* __restrict__ denom, float* __restrict__ accum) {
    int gid = blockIdx.x * 256 + threadIdx.x;
    int e = gid >> 5, c = gid & 31;
    if (e >= EE + NN) return;
    int src, dst;
    if (e < EE) { src = ei[e]; dst = ei[EE + e]; }
    else        { src = e - EE; dst = src; }          // self-loops
    float s = a_s[src] + a_d[dst];
    float le = (s > 0.f) ? s : 0.2f * s;              // leaky_relu 0.2
    float ex = __expf(le);                             // softmax shift cancels exactly
    unsafeAtomicAdd(&accum[dst * 32 + c], ex * h[src * 32 + c]);
    if (c == 0) unsafeAtomicAdd(&denom[dst], ex);
}

// ---------------- residual = X_t - concat([gat_out, 0]) ----------------
__global__ void residual_kernel(const float* __restrict__ Xseq, const float* __restrict__ accum,
                                const float* __restrict__ denom, const float* __restrict__ bias,
                                float* __restrict__ res) {
    int idx = blockIdx.x * 256 + threadIdx.x;
    if (idx >= NN * 64) return;
    int n = idx >> 6, k = idx & 63;
    float xv = Xseq[(size_t)n * (TT * PP) + 63 * PP + k];
    float g = 0.f;
    if (k < 32) g = accum[n * 32 + k] / denom[n] + bias[k];
    res[idx] = xv - g;
}

// ---------------- projections -> raw features in d_out ----------------
__global__ void proj_kernel(const float* __restrict__ ht, const float* __restrict__ hcs,
                            const float* __restrict__ Wt, const float* __restrict__ bt,
                            const float* __restrict__ Wc, const float* __restrict__ bc,
                            float* __restrict__ out) {
    __shared__ float sW[32][129];
    __shared__ float sb[32];
    int tid = threadIdx.x;
    for (int i = tid; i < 16 * 128; i += 256) {
        sW[i >> 7][i & 127] = Wt[i];
        sW[16 + (i >> 7)][i & 127] = Wc[i];
    }
    if (tid < 16) { sb[tid] = bt[tid]; sb[16 + tid] = bc[tid]; }
    __syncthreads();
    int idx = blockIdx.x * 256 + tid;
    int n = idx >> 5, c = idx & 31;
    const float* hrow = ((c < 16) ? ht : hcs) + (size_t)n * HH;
    const float* wrow = sW[c];
    float acc = sb[c];
    #pragma unroll 8
    for (int k = 0; k < 128; ++k) acc += hrow[k] * wrow[k];
    out[idx] = acc;
}

// ---------------- batchnorm stats (one block per column, no atomics) ----------------
__global__ void bn_stats_kernel(const float* __restrict__ raw,
                                const float* __restrict__ g1, const float* __restrict__ b1,
                                const float* __restrict__ g2, const float* __restrict__ b2,
                                float* __restrict__ ss) {
    int c = blockIdx.x;
    int tid = threadIdx.x;
    float s = 0.f, q = 0.f;
    for (int n = tid; n < NN; n += 256) {
        float v = raw[n * 32 + c];
        s += v; q += v * v;
    }
    __shared__ float ls[256], lq[256];
    ls[tid] = s; lq[tid] = q;
    __syncthreads();
    for (int st = 128; st > 0; st >>= 1) {
        if (tid < st) { ls[tid] += ls[tid + st]; lq[tid] += lq[tid + st]; }
        __syncthreads();
    }
    if (tid == 0) {
        float m = ls[0] / (float)NN;
        float var = lq[0] / (float)NN - m * m;      // biased var, matches jnp.var
        float istd = rsqrtf(var + 1e-5f);
        float gg = (c < 16) ? g1[c] : g2[c - 16];
        float bb = (c < 16) ? b1[c] : b2[c - 16];
        float sc = istd * gg;
        ss[c] = sc;
        ss[32 + c] = bb - m * sc;
    }
}

__global__ void bn_apply_kernel(float* __restrict__ out, const float* __restrict__ ss) {
    int idx = blockIdx.x * 256 + threadIdx.x;
    if (idx >= NN * 32) return;
    int c = idx & 31;
    out[idx] = out[idx] * ss[c] + ss[32 + c];
}

extern "C" void kernel_launch(void* const* d_in, const int* in_sizes, int n_in,
                              void* d_out, int out_size, void* d_ws, size_t ws_size,
                              hipStream_t stream) {
    const float* Xseq  = (const float*)d_in[0];
    const int*   ei    = (const int*)d_in[1];
    const float* tWih0 = (const float*)d_in[2];
    const float* tWhh0 = (const float*)d_in[3];
    const float* tbih0 = (const float*)d_in[4];
    const float* tbhh0 = (const float*)d_in[5];
    const float* tWih1 = (const float*)d_in[6];
    const float* tWhh1 = (const float*)d_in[7];
    const float* tbih1 = (const float*)d_in[8];
    const float* tbhh1 = (const float*)d_in[9];
    const float* cWih0 = (const float*)d_in[10];
    const float* cWhh0 = (const float*)d_in[11];
    const float* cbih0 = (const float*)d_in[12];
    const float* cbhh0 = (const float*)d_in[13];
    const float* cWih1 = (const float*)d_in[14];
    const float* cWhh1 = (const float*)d_in[15];
    const float* cbih1 = (const float*)d_in[16];
    const float* cbhh1 = (const float*)d_in[17];
    const float* gatW  = (const float*)d_in[18];
    const float* atts  = (const float*)d_in[19];
    const float* attd  = (const float*)d_in[20];
    const float* gatb  = (const float*)d_in[21];
    const float* ptW   = (const float*)d_in[22];
    const float* ptb   = (const float*)d_in[23];
    const float* pcW   = (const float*)d_in[24];
    const float* pcb   = (const float*)d_in[25];
    const float* bn1g  = (const float*)d_in[26];
    const float* bn1b  = (const float*)d_in[27];
    const float* bn2g  = (const float*)d_in[28];
    const float* bn2b  = (const float*)d_in[29];

    char* ws = (char*)d_ws;                       // total use ~16.2 MB
    _Float16* Wt0 = (_Float16*)(ws);              // 384*192*2 = 147456
    _Float16* Wt1 = (_Float16*)(ws + 147456);     // 384*256*2 = 196608
    _Float16* Wc0 = (_Float16*)(ws + 344064);
    _Float16* Wc1 = (_Float16*)(ws + 491520);
    float* h_t   = (float*)(ws + 688128);         // 10000*128*4
    float* h_cs  = (float*)(ws + 5808128);
    float* gath  = (float*)(ws + 10928128);       // 10000*32*4
    float* a_s   = (float*)(ws + 12208128);
    float* a_d   = (float*)(ws + 12248128);
    float* denom = (float*)(ws + 12288128);
    float* accum = (float*)(ws + 12328128);       // 10000*32*4
    float* resid = (float*)(ws + 13608128);       // 10000*64*4
    float* ss    = (float*)(ws + 16168128);       // 64 floats

    pack_w_kernel<<<288, 256, 0, stream>>>(tWih0, 64,  tWhh0, Wt0, 384 * 192);
    pack_w_kernel<<<384, 256, 0, stream>>>(tWih1, 128, tWhh1, Wt1, 384 * 256);
    pack_w_kernel<<<288, 256, 0, stream>>>(cWih0, 64,  cWhh0, Wc0, 384 * 192);
    pack_w_kernel<<<384, 256, 0, stream>>>(cWih1, 128, cWhh1, Wc1, 384 * 256);

    gru2_t8_kernel<<<625, 512, 0, stream>>>(Xseq, TT, TT * PP, Wt0, tbih0, tbhh0,
                                            Wt1, tbih1, tbhh1, h_t);

    gat_node_kernel<<<1250, 256, 0, stream>>>(Xseq, gatW, atts, attd, gath, a_s, a_d, denom, accum);
    gat_edge_kernel<<<41250, 256, 0, stream>>>(ei, a_s, a_d, gath, denom, accum);
    residual_kernel<<<2500, 256, 0, stream>>>(Xseq, accum, denom, gatb, resid);

    gru2_t8_kernel<<<625, 512, 0, stream>>>(resid, 1, PP, Wc0, cbih0, cbhh0,
                                            Wc1, cbih1, cbhh1, h_cs);

    proj_kernel<<<1250, 256, 0, stream>>>(h_t, h_cs, ptW, ptb, pcW, pcb, (float*)d_out);
    bn_stats_kernel<<<32, 256, 0, stream>>>((const float*)d_out, bn1g, bn1b, bn2g, bn2b, ss);
    bn_apply_kernel<<<1250, 256, 0, stream>>>((float*)d_out, ss);
}

// Round 18
// 506.131 us; speedup vs baseline: 1.5114x; 1.1683x over previous
//
#include <hip/hip_runtime.h>
#include <hip/hip_fp16.h>

#define NN 10000
#define TT 64
#define PP 64
#define HH 128
#define EE 320000

typedef _Float16 half8 __attribute__((ext_vector_type(8)));
typedef float f32x4 __attribute__((ext_vector_type(4)));

// gates: hardware exp + v_rcp_f32 divide (R15-proven: absmax 0.031 < 0.105)
__device__ __forceinline__ float sigm(float x) {
    return __builtin_amdgcn_rcpf(1.0f + __expf(-x));
}
__device__ __forceinline__ float tanh_(float x) {
    return 1.0f - 2.0f * __builtin_amdgcn_rcpf(__expf(2.0f * x) + 1.0f);
}
// swizzled byte offset into a [rows][128] fp16 LDS tile (row stride 256B).
__device__ __forceinline__ int hswz(int row, int colbyte) {
    return row * 256 + (colbyte ^ ((row & 7) << 4));
}

// ---------------- weight pack: [Wih | Whh] row-major -> fp16 ----------------
__global__ void pack_w_kernel(const float* __restrict__ Wa, int Ka,
                              const float* __restrict__ Wb,
                              _Float16* __restrict__ out, int total) {
    int idx = blockIdx.x * 256 + threadIdx.x;
    if (idx >= total) return;
    int K = Ka + HH;
    int r = idx / K, k = idx - r * K;
    float v = (k < Ka) ? Wa[r * Ka + k] : Wb[r * HH + (k - Ka)];
    out[idx] = (_Float16)v;
}

// -- fused 2-layer GRU: 8 waves x 1 triple, 2 waves/SIMD, resident weights --
// R15 VERBATIM (best verified: 472us gru_t). R17's hoist/share/setprio edits
// stretched live ranges -> scratch (WRITE 7.5->17.5MB) -> regression. At
// 2 waves/SIMD the v-file has zero slack; do not extend live ranges.
// Resident: 36 frags (L0h 12 + L1 24) = 144 regs "+a"; L0 x-part in LDS;
// carried hp; rcp gates; 65 single-barrier phases, L1 first.
__global__ __launch_bounds__(512, 2) void gru2_t8_kernel(
    const float* __restrict__ x, int T, int xstride,
    const _Float16* __restrict__ W0,  // [384][192]  (64 x | 128 h)
    const float* __restrict__ bih0, const float* __restrict__ bhh0,
    const _Float16* __restrict__ W1,  // [384][256]  (128 y0 | 128 h)
    const float* __restrict__ bih1, const float* __restrict__ bhh1,
    float* __restrict__ hout)         // [NN][128] f32
{
    __shared__ __align__(16) char lds[65536];  // [0,16K) h ping-pong | [16K,64K) W0x
    char* const WX = lds + 16384;
    const int tid = threadIdx.x;
    const int wv = tid >> 6;          // 0..7 = gate-col triple
    const int lane = tid & 63;
    const int l15 = lane & 15, lg = lane >> 4;
    const int rowbase = blockIdx.x * 16;
    const int col = wv * 16 + l15;

    for (int i = tid; i < 4096; i += 512) ((int*)lds)[i] = 0;

    // ---- stage L0 x-part weights (6 frags/wave) into LDS ----
    #pragma unroll
    for (int g = 0; g < 3; ++g) {
        const _Float16* r0 = W0 + ((size_t)((g * 8 + wv) * 16 + l15)) * 192;
        #pragma unroll
        for (int kt = 0; kt < 2; ++kt)
            *(half8*)(WX + wv * 6144 + (g * 2 + kt) * 1024 + lane * 16) =
                *(const half8*)(r0 + kt * 32 + lg * 8);
    }

    // ---- resident weights: L0 h-part (12) + L1 (24), pinned "+a" (144 regs) ----
    half8 w0h[3][4], w1[3][8];
    #pragma unroll
    for (int g = 0; g < 3; ++g) {
        const _Float16* r0 = W0 + ((size_t)((g * 8 + wv) * 16 + l15)) * 192;
        #pragma unroll
        for (int kt = 0; kt < 4; ++kt) w0h[g][kt] = *(const half8*)(r0 + 64 + kt * 32 + lg * 8);
        const _Float16* r1 = W1 + ((size_t)((g * 8 + wv) * 16 + l15)) * 256;
        #pragma unroll
        for (int kt = 0; kt < 8; ++kt) w1[g][kt] = *(const half8*)(r1 + kt * 32 + lg * 8);
    }
    #pragma unroll
    for (int g = 0; g < 3; ++g) {
        #pragma unroll
        for (int kt = 0; kt < 4; ++kt) asm volatile("" : "+a"(w0h[g][kt]));
        #pragma unroll
        for (int kt = 0; kt < 8; ++kt) asm volatile("" : "+a"(w1[g][kt]));
    }

    // ---- biases folded into accumulator init (n split: n = tanh(i_n + r*h_n)) ----
    const float br0  = bih0[col] + bhh0[col];
    const float bz0  = bih0[128 + col] + bhh0[128 + col];
    const float bni0 = bih0[256 + col];
    const float bnh0 = bhh0[256 + col];
    const float br1  = bih1[col] + bhh1[col];
    const float bz1  = bih1[128 + col] + bhh1[128 + col];
    const float bni1 = bih1[256 + col];
    const float bnh1 = bhh1[256 + col];

    const float* xr = x + (size_t)(rowbase + l15) * xstride;

    float hp0[4] = {0.f, 0.f, 0.f, 0.f};
    float hp1[4] = {0.f, 0.f, 0.f, 0.f};

    __syncthreads();

    for (int it = 0; it <= T; ++it) {
        const int off = (it & 1) * 4096;
        char* const H0r = lds + off;                 // h0(it-1) == y0(it-1)
        char* const H0w = lds + (4096 - off);        // h0(it)
        char* const H1r = lds + 8192 + off;          // h1(it-2)
        char* const H1w = lds + 8192 + (4096 - off); // h1(it-1)

        // issue x(it) loads early; consumed after L1 (latency cover)
        float4 xu0, xv0, xu1, xv1;
        if (it < T) {
            const float* p = xr + it * PP;
            xu0 = *(const float4*)(p + lg * 8);
            xv0 = *(const float4*)(p + lg * 8 + 4);
            xu1 = *(const float4*)(p + 32 + lg * 8);
            xv1 = *(const float4*)(p + 32 + lg * 8 + 4);
        }

        // ============ layer 1: h1(it-1) = f(y0(it-1), h1(it-2)) ============
        if (it >= 1) {
            f32x4 ar  = {br1, br1, br1, br1};
            f32x4 az  = {bz1, bz1, bz1, bz1};
            f32x4 ani = {bni1, bni1, bni1, bni1};
            f32x4 anh = {bnh1, bnh1, bnh1, bnh1};
            #pragma unroll
            for (int kt = 0; kt < 4; ++kt) {
                const int boff = (kt * 32 + lg * 8) * 2;
                half8 ay  = *(const half8*)(H0r + hswz(l15, boff));
                half8 ah1 = *(const half8*)(H1r + hswz(l15, boff));
                ar  = __builtin_amdgcn_mfma_f32_16x16x32_f16(ay,  w1[0][kt],   ar, 0,0,0);
                ar  = __builtin_amdgcn_mfma_f32_16x16x32_f16(ah1, w1[0][4+kt], ar, 0,0,0);
                az  = __builtin_amdgcn_mfma_f32_16x16x32_f16(ay,  w1[1][kt],   az, 0,0,0);
                az  = __builtin_amdgcn_mfma_f32_16x16x32_f16(ah1, w1[1][4+kt], az, 0,0,0);
                ani = __builtin_amdgcn_mfma_f32_16x16x32_f16(ay,  w1[2][kt],   ani, 0,0,0);
                anh = __builtin_amdgcn_mfma_f32_16x16x32_f16(ah1, w1[2][4+kt], anh, 0,0,0);
            }
            #pragma unroll
            for (int r = 0; r < 4; ++r) {
                float rg = sigm(ar[r]);
                float zg = sigm(az[r]);
                float ng = tanh_(ani[r] + rg * anh[r]);
                float hv = ng + zg * (hp1[r] - ng);
                hp1[r] = hv;
                *(_Float16*)(H1w + hswz(lg * 4 + r, col * 2)) = (_Float16)hv;
            }
        }

        // ============ layer 0: h0(it) = f(x(it), h0(it-1)) ============
        if (it < T) {
            half8 ax0, ax1;
            ax0[0]=(_Float16)xu0.x; ax0[1]=(_Float16)xu0.y; ax0[2]=(_Float16)xu0.z; ax0[3]=(_Float16)xu0.w;
            ax0[4]=(_Float16)xv0.x; ax0[5]=(_Float16)xv0.y; ax0[6]=(_Float16)xv0.z; ax0[7]=(_Float16)xv0.w;
            ax1[0]=(_Float16)xu1.x; ax1[1]=(_Float16)xu1.y; ax1[2]=(_Float16)xu1.z; ax1[3]=(_Float16)xu1.w;
            ax1[4]=(_Float16)xv1.x; ax1[5]=(_Float16)xv1.y; ax1[6]=(_Float16)xv1.z; ax1[7]=(_Float16)xv1.w;
            f32x4 ar  = {br0, br0, br0, br0};
            f32x4 az  = {bz0, bz0, bz0, bz0};
            f32x4 ani = {bni0, bni0, bni0, bni0};
            f32x4 anh = {bnh0, bnh0, bnh0, bnh0};
            // x-part: B-frags from LDS (staged once)
            #pragma unroll
            for (int kt = 0; kt < 2; ++kt) {
                const char* wb = WX + wv * 6144 + kt * 1024 + lane * 16;
                half8 wxr = *(const half8*)(wb);
                half8 wxz = *(const half8*)(wb + 2048);
                half8 wxn = *(const half8*)(wb + 4096);
                half8 ax = (kt == 0) ? ax0 : ax1;
                ar  = __builtin_amdgcn_mfma_f32_16x16x32_f16(ax, wxr, ar, 0,0,0);
                az  = __builtin_amdgcn_mfma_f32_16x16x32_f16(ax, wxz, az, 0,0,0);
                ani = __builtin_amdgcn_mfma_f32_16x16x32_f16(ax, wxn, ani, 0,0,0);
            }
            // h-part: resident B-frags
            #pragma unroll
            for (int kt = 0; kt < 4; ++kt) {
                half8 ah = *(const half8*)(H0r + hswz(l15, (kt * 32 + lg * 8) * 2));
                ar  = __builtin_amdgcn_mfma_f32_16x16x32_f16(ah, w0h[0][kt], ar, 0,0,0);
                az  = __builtin_amdgcn_mfma_f32_16x16x32_f16(ah, w0h[1][kt], az, 0,0,0);
                anh = __builtin_amdgcn_mfma_f32_16x16x32_f16(ah, w0h[2][kt], anh, 0,0,0);
            }
            #pragma unroll
            for (int r = 0; r < 4; ++r) {
                float rg = sigm(ar[r]);
                float zg = sigm(az[r]);
                float ng = tanh_(ani[r] + rg * anh[r]);
                float hv = ng + zg * (hp0[r] - ng);
                hp0[r] = hv;
                *(_Float16*)(H0w + hswz(lg * 4 + r, col * 2)) = (_Float16)hv;
            }
        }
        __syncthreads();
    }

    // final h1 from carried registers
    #pragma unroll
    for (int r = 0; r < 4; ++r)
        hout[(size_t)(rowbase + lg * 4 + r) * HH + col] = hp1[r];
}

// ---- dedicated single-step 2-layer GRU for the cross-section path (h=0) ----
// With h0=h1=0: gh = bhh exactly, h_new = (1-z)*n. Two small fused GEMMs;
// weights streamed from L2 (single pass, no residency needed). 8 waves x
// 1 triple, 16 rows/block, one barrier.
__global__ __launch_bounds__(512) void gru_cs_step_kernel(
    const float* __restrict__ xin,    // resid [NN][64]
    const _Float16* __restrict__ W0,  // [384][192]
    const float* __restrict__ bih0, const float* __restrict__ bhh0,
    const _Float16* __restrict__ W1,  // [384][256]
    const float* __restrict__ bih1, const float* __restrict__ bhh1,
    float* __restrict__ hout)         // h_cs [NN][128] f32
{
    __shared__ __align__(16) char lds[4096];   // y0 tile 16x128 fp16 (hswz)
    const int tid = threadIdx.x;
    const int wv = tid >> 6;
    const int lane = tid & 63;
    const int l15 = lane & 15, lg = lane >> 4;
    const int rowbase = blockIdx.x * 16;
    const int col = wv * 16 + l15;

    const float br0  = bih0[col] + bhh0[col];
    const float bz0  = bih0[128 + col] + bhh0[128 + col];
    const float bni0 = bih0[256 + col];
    const float bnh0 = bhh0[256 + col];
    const float br1  = bih1[col] + bhh1[col];
    const float bz1  = bih1[128 + col] + bhh1[128 + col];
    const float bni1 = bih1[256 + col];
    const float bnh1 = bhh1[256 + col];

    // ---- layer 0: gi = x @ W0x^T (K=64); gh = bhh0 ----
    const float* xr = xin + (size_t)(rowbase + l15) * PP;
    float4 u0 = *(const float4*)(xr + lg * 8);
    float4 v0 = *(const float4*)(xr + lg * 8 + 4);
    float4 u1 = *(const float4*)(xr + 32 + lg * 8);
    float4 v1 = *(const float4*)(xr + 32 + lg * 8 + 4);
    half8 ax0, ax1;
    ax0[0]=(_Float16)u0.x; ax0[1]=(_Float16)u0.y; ax0[2]=(_Float16)u0.z; ax0[3]=(_Float16)u0.w;
    ax0[4]=(_Float16)v0.x; ax0[5]=(_Float16)v0.y; ax0[6]=(_Float16)v0.z; ax0[7]=(_Float16)v0.w;
    ax1[0]=(_Float16)u1.x; ax1[1]=(_Float16)u1.y; ax1[2]=(_Float16)u1.z; ax1[3]=(_Float16)u1.w;
    ax1[4]=(_Float16)v1.x; ax1[5]=(_Float16)v1.y; ax1[6]=(_Float16)v1.z; ax1[7]=(_Float16)v1.w;

    f32x4 ar = {br0, br0, br0, br0};
    f32x4 az = {bz0, bz0, bz0, bz0};
    f32x4 ani = {bni0, bni0, bni0, bni0};
    #pragma unroll
    for (int g = 0; g < 3; ++g) {
        const _Float16* r0 = W0 + ((size_t)((g * 8 + wv) * 16 + l15)) * 192;
        half8 wk0 = *(const half8*)(r0 + lg * 8);
        half8 wk1 = *(const half8*)(r0 + 32 + lg * 8);
        f32x4* dst = (g == 0) ? &ar : (g == 1) ? &az : &ani;
        *dst = __builtin_amdgcn_mfma_f32_16x16x32_f16(ax0, wk0, *dst, 0,0,0);
        *dst = __builtin_amdgcn_mfma_f32_16x16x32_f16(ax1, wk1, *dst, 0,0,0);
    }
    #pragma unroll
    for (int r = 0; r < 4; ++r) {
        float rg = sigm(ar[r]);
        float zg = sigm(az[r]);
        float ng = tanh_(ani[r] + rg * bnh0);
        float hv = (1.0f - zg) * ng;          // h0 = 0
        *(_Float16*)(lds + hswz(lg * 4 + r, col * 2)) = (_Float16)hv;
    }
    __syncthreads();

    // ---- layer 1: gi = y0 @ W1y^T (K=128); gh = bhh1 ----
    half8 ay[4];
    #pragma unroll
    for (int kt = 0; kt < 4; ++kt)
        ay[kt] = *(const half8*)(lds + hswz(l15, (kt * 32 + lg * 8) * 2));
    f32x4 ar1 = {br1, br1, br1, br1};
    f32x4 az1 = {bz1, bz1, bz1, bz1};
    f32x4 ani1 = {bni1, bni1, bni1, bni1};
    #pragma unroll
    for (int g = 0; g < 3; ++g) {
        const _Float16* r1 = W1 + ((size_t)((g * 8 + wv) * 16 + l15)) * 256;
        f32x4* dst = (g == 0) ? &ar1 : (g == 1) ? &az1 : &ani1;
        #pragma unroll
        for (int kt = 0; kt < 4; ++kt) {
            half8 wk = *(const half8*)(r1 + kt * 32 + lg * 8);
            *dst = __builtin_amdgcn_mfma_f32_16x16x32_f16(ay[kt], wk, *dst, 0,0,0);
        }
    }
    #pragma unroll
    for (int r = 0; r < 4; ++r) {
        float rg = sigm(ar1[r]);
        float zg = sigm(az1[r]);
        float ng = tanh_(ani1[r] + rg * bnh1);
        float hv = (1.0f - zg) * ng;          // h1 = 0
        hout[(size_t)(rowbase + lg * 4 + r) * HH + col] = hv;
    }
}

// ---------------- GAT: per-node h, attention logits, zero accumulators ----------------
__global__ void gat_node_kernel(const float* __restrict__ Xseq, const float* __restrict__ W,
                                const float* __restrict__ att_s, const float* __restrict__ att_d,
                                float* __restrict__ h, float* __restrict__ a_s, float* __restrict__ a_d,
                                float* __restrict__ denom, float* __restrict__ accum) {
    __shared__ float sW[64][33];
    __shared__ float sas[32], sad[32];
    int tid = threadIdx.x;
    for (int i = tid; i < 64 * 32; i += 256) sW[i >> 5][i & 31] = W[i];
    if (tid < 32) { sas[tid] = att_s[tid]; sad[tid] = att_d[tid]; }
    __syncthreads();
    int c = tid & 31;
    int n = blockIdx.x * 8 + (tid >> 5);
    const float* xr = Xseq + (size_t)n * (TT * PP) + 63 * PP;
    float acc = 0.f;
    #pragma unroll
    for (int k = 0; k < 64; ++k) acc += xr[k] * sW[k][c];
    h[n * 32 + c] = acc;
    accum[n * 32 + c] = 0.f;
    float ps = acc * sas[c];
    float pd = acc * sad[c];
    #pragma unroll
    for (int m = 16; m > 0; m >>= 1) { ps += __shfl_xor(ps, m, 32); pd += __shfl_xor(pd, m, 32); }
    if (c == 0) { a_s[n] = ps; a_d[n] = pd; denom[n] = 0.f; }
}

// ---------------- GAT: fused edge pass (denom + weighted accum; div postponed) ----------------
__global__ void gat_edge_kernel(const int* __restrict__ ei,
                                const float* __restrict__ a_s, const float* __restrict__ a_d,
                                const float* __restrict__ h,
                                float* __restrict__ denom, float* __restrict__ accum) {
    int gid = blockIdx.x * 256 + threadIdx.x;
    int e = gid >> 5, c = gid & 31;
    if (e >= EE + NN) return;
    int src, dst;
    if (e < EE) { src = ei[e]; dst = ei[EE + e]; }
    else        { src = e - EE; dst = src; }          // self-loops
    float s = a_s[src] + a_d[dst];
    float le = (s > 0.f) ? s : 0.2f * s;              // leaky_relu 0.2
    float ex = __expf(le);                             // softmax shift cancels exactly
    unsafeAtomicAdd(&accum[dst * 32 + c], ex * h[src * 32 + c]);
    if (c == 0) unsafeAtomicAdd(&denom[dst], ex);
}

// ---------------- residual = X_t - concat([gat_out, 0]) ----------------
__global__ void residual_kernel(const float* __restrict__ Xseq, const float* __restrict__ accum,
                                const float* __restrict__ denom, const float* __restrict__ bias,
                                float* __restrict__ res) {
    int idx = blockIdx.x * 256 + threadIdx.x;
    if (idx >= NN * 64) return;
    int n = idx >> 6, k = idx & 63;
    float xv = Xseq[(size_t)n * (TT * PP) + 63 * PP + k];
    float g = 0.f;
    if (k < 32) g = accum[n * 32 + k] / denom[n] + bias[k];
    res[idx] = xv - g;
}

// ---------------- projections -> raw features in d_out ----------------
__global__ void proj_kernel(const float* __restrict__ ht, const float* __restrict__ hcs,
                            const float* __restrict__ Wt, const float* __restrict__ bt,
                            const float* __restrict__ Wc, const float* __restrict__ bc,
                            float* __restrict__ out) {
    __shared__ float sW[32][129];
    __shared__ float sb[32];
    int tid = threadIdx.x;
    for (int i = tid; i < 16 * 128; i += 256) {
        sW[i >> 7][i & 127] = Wt[i];
        sW[16 + (i >> 7)][i & 127] = Wc[i];
    }
    if (tid < 16) { sb[tid] = bt[tid]; sb[16 + tid] = bc[tid]; }
    __syncthreads();
    int idx = blockIdx.x * 256 + tid;
    int n = idx >> 5, c = idx & 31;
    const float* hrow = ((c < 16) ? ht : hcs) + (size_t)n * HH;
    const float* wrow = sW[c];
    float acc = sb[c];
    #pragma unroll 8
    for (int k = 0; k < 128; ++k) acc += hrow[k] * wrow[k];
    out[idx] = acc;
}

// ---------------- batchnorm stats (one block per column, no atomics) ----------------
__global__ void bn_stats_kernel(const float* __restrict__ raw,
                                const float* __restrict__ g1, const float* __restrict__ b1,
                                const float* __restrict__ g2, const float* __restrict__ b2,
                                float* __restrict__ ss) {
    int c = blockIdx.x;
    int tid = threadIdx.x;
    float s = 0.f, q = 0.f;
    for (int n = tid; n < NN; n += 256) {
        float v = raw[n * 32 + c];
        s += v; q += v * v;
    }
    __shared__ float ls[256], lq[256];
    ls[tid] = s; lq[tid] = q;
    __syncthreads();
    for (int st = 128; st > 0; st >>= 1) {
        if (tid < st) { ls[tid] += ls[tid + st]; lq[tid] += lq[tid + st]; }
        __syncthreads();
    }
    if (tid == 0) {
        float m = ls[0] / (float)NN;
        float var = lq[0] / (float)NN - m * m;      // biased var, matches jnp.var
        float istd = rsqrtf(var + 1e-5f);
        float gg = (c < 16) ? g1[c] : g2[c - 16];
        float bb = (c < 16) ? b1[c] : b2[c - 16];
        float sc = istd * gg;
        ss[c] = sc;
        ss[32 + c] = bb - m * sc;
    }
}

__global__ void bn_apply_kernel(float* __restrict__ out, const float* __restrict__ ss) {
    int idx = blockIdx.x * 256 + threadIdx.x;
    if (idx >= NN * 32) return;
    int c = idx & 31;
    out[idx] = out[idx] * ss[c] + ss[32 + c];
}

extern "C" void kernel_launch(void* const* d_in, const int* in_sizes, int n_in,
                              void* d_out, int out_size, void* d_ws, size_t ws_size,
                              hipStream_t stream) {
    const float* Xseq  = (const float*)d_in[0];
    const int*   ei    = (const int*)d_in[1];
    const float* tWih0 = (const float*)d_in[2];
    const float* tWhh0 = (const float*)d_in[3];
    const float* tbih0 = (const float*)d_in[4];
    const float* tbhh0 = (const float*)d_in[5];
    const float* tWih1 = (const float*)d_in[6];
    const float* tWhh1 = (const float*)d_in[7];
    const float* tbih1 = (const float*)d_in[8];
    const float* tbhh1 = (const float*)d_in[9];
    const float* cWih0 = (const float*)d_in[10];
    const float* cWhh0 = (const float*)d_in[11];
    const float* cbih0 = (const float*)d_in[12];
    const float* cbhh0 = (const float*)d_in[13];
    const float* cWih1 = (const float*)d_in[14];
    const float* cWhh1 = (const float*)d_in[15];
    const float* cbih1 = (const float*)d_in[16];
    const float* cbhh1 = (const float*)d_in[17];
    const float* gatW  = (const float*)d_in[18];
    const float* atts  = (const float*)d_in[19];
    const float* attd  = (const float*)d_in[20];
    const float* gatb  = (const float*)d_in[21];
    const float* ptW   = (const float*)d_in[22];
    const float* ptb   = (const float*)d_in[23];
    const float* pcW   = (const float*)d_in[24];
    const float* pcb   = (const float*)d_in[25];
    const float* bn1g  = (const float*)d_in[26];
    const float* bn1b  = (const float*)d_in[27];
    const float* bn2g  = (const float*)d_in[28];
    const float* bn2b  = (const float*)d_in[29];

    char* ws = (char*)d_ws;                       // total use ~16.2 MB
    _Float16* Wt0 = (_Float16*)(ws);              // 384*192*2 = 147456
    _Float16* Wt1 = (_Float16*)(ws + 147456);     // 384*256*2 = 196608
    _Float16* Wc0 = (_Float16*)(ws + 344064);
    _Float16* Wc1 = (_Float16*)(ws + 491520);
    float* h_t   = (float*)(ws + 688128);         // 10000*128*4
    float* h_cs  = (float*)(ws + 5808128);
    float* gath  = (float*)(ws + 10928128);       // 10000*32*4
    float* a_s   = (float*)(ws + 12208128);
    float* a_d   = (float*)(ws + 12248128);
    float* denom = (float*)(ws + 12288128);
    float* accum = (float*)(ws + 12328128);       // 10000*32*4
    float* resid = (float*)(ws + 13608128);       // 10000*64*4
    float* ss    = (float*)(ws + 16168128);       // 64 floats

    pack_w_kernel<<<288, 256, 0, stream>>>(tWih0, 64,  tWhh0, Wt0, 384 * 192);
    pack_w_kernel<<<384, 256, 0, stream>>>(tWih1, 128, tWhh1, Wt1, 384 * 256);
    pack_w_kernel<<<288, 256, 0, stream>>>(cWih0, 64,  cWhh0, Wc0, 384 * 192);
    pack_w_kernel<<<384, 256, 0, stream>>>(cWih1, 128, cWhh1, Wc1, 384 * 256);

    gru2_t8_kernel<<<625, 512, 0, stream>>>(Xseq, TT, TT * PP, Wt0, tbih0, tbhh0,
                                            Wt1, tbih1, tbhh1, h_t);

    gat_node_kernel<<<1250, 256, 0, stream>>>(Xseq, gatW, atts, attd, gath, a_s, a_d, denom, accum);
    gat_edge_kernel<<<41250, 256, 0, stream>>>(ei, a_s, a_d, gath, denom, accum);
    residual_kernel<<<2500, 256, 0, stream>>>(Xseq, accum, denom, gatb, resid);

    gru_cs_step_kernel<<<625, 512, 0, stream>>>(resid, Wc0, cbih0, cbhh0,
                                                Wc1, cbih1, cbhh1, h_cs);

    proj_kernel<<<1250, 256, 0, stream>>>(h_t, h_cs, ptW, ptb, pcW, pcb, (float*)d_out);
    bn_stats_kernel<<<32, 256, 0, stream>>>((const float*)d_out, bn1g, bn1b, bn2g, bn2b, ss);
    bn_apply_kernel<<<1250, 256, 0, stream>>>((float*)d_out, ss);
}